// Round 6
// baseline (355.252 us; speedup 1.0000x reference)
//
#include <hip/hip_runtime.h>
#include <hip/hip_bf16.h>
#include <math.h>

using bf16 = __hip_bfloat16;

typedef __bf16 bf16x8 __attribute__((ext_vector_type(8)));
typedef __bf16 bf16x4 __attribute__((ext_vector_type(4)));
typedef float  f32x4  __attribute__((ext_vector_type(4)));
typedef float  f32x16 __attribute__((ext_vector_type(16)));

constexpr int Bb = 2;
constexpr int Ts = 2048;
constexpr int Cc = 1024;
constexpr int Hh = 16;
constexpr int Dh = 64;
constexpr int Mm = Bb * Ts;        // 4096 rows of x
constexpr int Nqkv = 3 * Cc;       // 3072
constexpr int BHTD = Bb * Hh * Ts * Dh;  // elements per Q/K/V tensor

// async global->LDS, 16B per lane; LDS dest = wave-uniform base + lane*16
__device__ __forceinline__
void gll16(const __bf16* g, __bf16* l)
{
    __builtin_amdgcn_global_load_lds(
        (const __attribute__((address_space(1))) unsigned int*)g,
        (__attribute__((address_space(3))) unsigned int*)l,
        16, 0, 0);
}

// ---------------------------------------------------------------------------
// Merged prep: [0,4096) cvt X fp32->bf16; [4096,4864) transpose W_qkv;
// [4864,5120) transpose W_proj.
// ---------------------------------------------------------------------------
__global__ __launch_bounds__(256)
void prep_all(const float* __restrict__ x, __bf16* __restrict__ Xb,
              const float* __restrict__ Wq, __bf16* __restrict__ Wqt,
              const float* __restrict__ Wp, __bf16* __restrict__ Wpt)
{
    __shared__ __bf16 tl[64][72];
    const int bid = blockIdx.x;
    const int t = threadIdx.x;

    if (bid < 4096) {
        int i = (bid * 256 + t) * 4;
        float4 v = *(const float4*)(x + i);
        bf16x4 o = { (__bf16)v.x, (__bf16)v.y, (__bf16)v.z, (__bf16)v.w };
        *(bf16x4*)(Xb + i) = o;
        return;
    }
    const float* W; __bf16* Wt; int cols, bx, by;
    if (bid < 4096 + 768) {
        W = Wq; Wt = Wqt; cols = Nqkv;
        bx = (bid - 4096) % 48; by = (bid - 4096) / 48;
    } else {
        W = Wp; Wt = Wpt; cols = Cc;
        bx = (bid - 4864) % 16; by = (bid - 4864) / 16;
    }
    const int c0 = bx * 64;   // N dim
    const int r0 = by * 64;   // K dim (1024)
    #pragma unroll
    for (int i = 0; i < 4; i++) {
        int e = t + 256 * i;
        int r = e >> 4, c4 = (e & 15) * 4;
        float4 v = *(const float4*)(W + (r0 + r) * cols + c0 + c4);
        bf16x4 o = { (__bf16)v.x, (__bf16)v.y, (__bf16)v.z, (__bf16)v.w };
        *(bf16x4*)&tl[r][c4] = o;
    }
    __syncthreads();
    #pragma unroll
    for (int i = 0; i < 4; i++) {
        int e = t + 256 * i;
        int n = e >> 4, k4 = (e & 15) * 4;
        bf16x4 o = { tl[k4][n], tl[k4 + 1][n], tl[k4 + 2][n], tl[k4 + 3][n] };
        *(bf16x4*)(Wt + (c0 + n) * 1024 + r0 + k4) = o;
    }
}

// ---------------------------------------------------------------------------
// MFMA GEMM core (R9-proven m97 structure), templated over BM (A-tile rows).
// BM=128: 4 waves x 64x64 (qkv, 3 blocks/CU). BM=64: 4 waves x 32x64
// (proj, 512-block grid -> 2 blocks/CU for cross-block overlap).
// BK=32, global_load_lds width-16 into unpadded LDS.
// C/D layout: col=l16, row=quad*4+r.
// ---------------------------------------------------------------------------
template<int BM>
__device__ __forceinline__
void gemm_core(const __bf16* __restrict__ A, const __bf16* __restrict__ Bt,
               int m0, int n0, int wm, int wn, int quad, int l16, int t,
               f32x4 (&acc)[4][4])
{
    __shared__ __bf16 Al[BM][32];
    __shared__ __bf16 Bl[128][32];

    constexpr int MT = BM / 32;        // m-subtiles per wave
    const int wave = t >> 6;
    const int lane = t & 63;
    const int srow = lane >> 2;        // 0..15
    const int scol = (lane & 3) * 8;   // 0,8,16,24

    const __bf16* Ag = A  + (size_t)(m0 + wave * 16 + srow) * 1024 + scol;
    const __bf16* Bg = Bt + (size_t)(n0 + wave * 16 + srow) * 1024 + scol;
    __bf16* Al_lo = &Al[wave * 16][0];
    __bf16* Bl_lo = &Bl[wave * 16][0];
    __bf16* Bl_hi = &Bl[64 + wave * 16][0];

    for (int k0 = 0; k0 < 1024; k0 += 32) {
        gll16(Ag + k0, Al_lo);
        if constexpr (BM == 128) {
            __bf16* Al_hi = &Al[64 + wave * 16][0];
            gll16(Ag + k0 + 64 * 1024, Al_hi);
        }
        gll16(Bg + k0,             Bl_lo);
        gll16(Bg + k0 + 64 * 1024, Bl_hi);
        __syncthreads();
        bf16x8 af[MT], bfr[4];
        #pragma unroll
        for (int mt = 0; mt < MT; mt++)
            af[mt] = *(const bf16x8*)&Al[wm * (BM / 2) + mt * 16 + l16][quad * 8];
        #pragma unroll
        for (int nt = 0; nt < 4; nt++)
            bfr[nt] = *(const bf16x8*)&Bl[wn * 64 + nt * 16 + l16][quad * 8];
        #pragma unroll
        for (int mt = 0; mt < MT; mt++)
            #pragma unroll
            for (int nt = 0; nt < 4; nt++)
                acc[mt][nt] = __builtin_amdgcn_mfma_f32_16x16x32_bf16(
                    af[mt], bfr[nt], acc[mt][nt], 0, 0, 0);
        __syncthreads();
    }
}

// QKV: bias + scatter. Q,K -> [B,H,T,Dh] via dedicated-LDS coalescing
// (bf16-typed wave-private buffer; NOT aliased with gemm staging);
// V -> [B,H,Dh,T] transposed, packed 8B direct stores.
__global__ __launch_bounds__(256)
void qkv_mfma(const __bf16* __restrict__ A, const __bf16* __restrict__ Bt,
              const float* __restrict__ bias, __bf16* __restrict__ qkv)
{
    __shared__ __bf16 ebuf[4][64][72];   // per-wave epilogue tile [m-row][d]

    const int t    = threadIdx.x;
    const int wave = t >> 6;
    const int lane = t & 63;
    const int quad = lane >> 4;
    const int l16  = lane & 15;
    const int wm   = wave >> 1, wn = wave & 1;
    const int n0 = blockIdx.x * 128;
    const int m0 = blockIdx.y * 128;

    f32x4 acc[4][4];
    #pragma unroll
    for (int i = 0; i < 4; i++)
        #pragma unroll
        for (int j = 0; j < 4; j++)
            acc[i][j] = f32x4{0.f, 0.f, 0.f, 0.f};

    gemm_core<128>(A, Bt, m0, n0, wm, wn, quad, l16, t, acc);

    // wave-uniform head info (wave n-range = 64 = one head's Dh)
    const int nw0 = n0 + wn * 64;
    const int which = nw0 >> 10;
    const int h = (nw0 & 1023) >> 6;

    if (which == 2) {
        // V^T: [b][h][d][tt], r=0..3 consecutive tt -> one 8B store
        #pragma unroll
        for (int nt = 0; nt < 4; nt++) {
            int d = nt * 16 + l16;
            float bs = bias[nw0 + nt * 16 + l16];
            #pragma unroll
            for (int mt = 0; mt < 4; mt++) {
                int m = m0 + wm * 64 + mt * 16 + quad * 4;
                int b = m >> 11;
                int tt = m & 2047;
                bf16x4 o = { (__bf16)(acc[mt][nt][0] + bs),
                             (__bf16)(acc[mt][nt][1] + bs),
                             (__bf16)(acc[mt][nt][2] + bs),
                             (__bf16)(acc[mt][nt][3] + bs) };
                *(bf16x4*)&qkv[2 * (size_t)BHTD +
                               (((size_t)(b * 16 + h) * 64 + d) * 2048 + tt)] = o;
            }
        }
    } else {
        // Q/K: stage wave's 64(m) x 64(d) tile in wave-private LDS,
        // then 8 coalesced 16B global stores per lane.
        #pragma unroll
        for (int nt = 0; nt < 4; nt++) {
            float bs = bias[nw0 + nt * 16 + l16];
            #pragma unroll
            for (int mt = 0; mt < 4; mt++)
                #pragma unroll
                for (int r = 0; r < 4; r++)
                    ebuf[wave][mt * 16 + quad * 4 + r][nt * 16 + l16] =
                        (__bf16)(acc[mt][nt][r] + bs);
        }
        // wave-private: compiler orders ds_write -> ds_read via lgkmcnt
        int m = m0 + wm * 64 + lane;
        int b = m >> 11;
        int tt = m & 2047;
        __bf16* dst = &qkv[which * (size_t)BHTD +
                           (((size_t)(b * 16 + h) * 2048 + tt) * 64)];
        #pragma unroll
        for (int c = 0; c < 8; c++)
            *(bf16x8*)(dst + c * 8) = *(const bf16x8*)&ebuf[wave][lane][c * 8];
    }
}

// Proj: bias + fp32 out [4096][1024]. BM=64 tile -> 512 blocks (2/CU).
__global__ __launch_bounds__(256)
void proj_mfma(const __bf16* __restrict__ A, const __bf16* __restrict__ Bt,
               const float* __restrict__ bias, float* __restrict__ out)
{
    const int t    = threadIdx.x;
    const int wave = t >> 6;
    const int lane = t & 63;
    const int quad = lane >> 4;
    const int l16  = lane & 15;
    const int wm   = wave >> 1, wn = wave & 1;
    const int n0 = blockIdx.x * 128;
    const int m0 = blockIdx.y * 64;

    f32x4 acc[4][4];
    #pragma unroll
    for (int i = 0; i < 4; i++)
        #pragma unroll
        for (int j = 0; j < 4; j++)
            acc[i][j] = f32x4{0.f, 0.f, 0.f, 0.f};

    gemm_core<64>(A, Bt, m0, n0, wm, wn, quad, l16, t, acc);

    #pragma unroll
    for (int nt = 0; nt < 4; nt++) {
        int n = n0 + wn * 64 + nt * 16 + l16;
        float bs = bias[n];
        #pragma unroll
        for (int mt = 0; mt < 2; mt++) {
            #pragma unroll
            for (int r = 0; r < 4; r++) {
                int m = m0 + wm * 32 + mt * 16 + quad * 4 + r;
                out[m * 1024 + n] = acc[mt][nt][r] + bs;
            }
        }
    }
}

// ===========================================================================
// MFMA flash attention v11 (R17): 4-way K-split, 16 waves/block (1024 thr),
// grid 256 (1 block/CU = 16 waves/CU = 4/SIMD). wave = (kh 0..3, qg 0..3):
// qg owns 64 q rows (v7 inner body, 64-q frag amortization preserved);
// kh owns 512 of 2048 k (8 chunks). This is the only decomposition giving
// BOTH 4 waves/SIMD (latency hiding; v7 had 2) AND 64 q/wave (LDS-read
// amortization; v9's 32 q/wave doubled LDS traffic).
// LDS: 4 kh x 2 buf x (8KB K + 8KB V) = 128 KB + 8 KB lsum = 136 KB.
// Race-free 1-barrier dbuf (v9 pattern): vmcnt(0) on own chunk-j loads ->
// s_barrier (also certifies prior readers of buf p^1 done) -> issue j+1.
// Max-free softmax => kh partials ADD; 2-step LDS tree at epilogue
// (kh=2 -> sK, kh=3 -> sV; kh=1 folds sV; kh=0 finishes).
// ===========================================================================
__global__ __launch_bounds__(1024, 4)
void attn_mfma(const __bf16* __restrict__ Q, const __bf16* __restrict__ K,
               const __bf16* __restrict__ VT, __bf16* __restrict__ O)
{
    __shared__ __bf16 sK[4][2][64 * 64];   // [kh][buf][k_local*64+d] swizzled
    __shared__ __bf16 sV[4][2][64 * 64];   // [kh][buf][d*64+k_local] swizzled
    __shared__ float  sLs[4][4][2][64];    // [kh][qg][qs][lane] lsum partials

    const int t    = threadIdx.x;
    const int wave = t >> 6;
    const int lane = t & 63;
    const int qg   = wave & 3;             // q-group 0..3
    const int kh   = wave >> 2;            // k-quarter 0..3
    const int c    = lane & 31;
    const int hi   = lane >> 5;
    const int hx   = hi * 16;              // byte offset of the 8-elem half
    const int sw   = (c & 7) << 4;         // read-side XOR swizzle

    const int blk = blockIdx.x;
    const int bh  = blk & 31;              // 32 ≡ 0 (mod 8): head stays XCD-local
    const int qc  = blk >> 5;              // 0..7
    const int q0  = qc * 256 + qg * 64;

    const __bf16* Qp = Q  + ((size_t)bh * Ts + q0) * Dh;
    const __bf16* Kp = K  + (size_t)bh * Ts * Dh;
    const __bf16* Vp = VT + (size_t)bh * Dh * Ts;   // [64][2048]

    // Q fragments (B-operand of mfma(K,Q)), pre-scaled by log2e/sqrt(Dh)
    const float qscale = 0.125f * 1.44269504088896f;
    bf16x8 qf[2][4];
    #pragma unroll
    for (int qs = 0; qs < 2; qs++)
        #pragma unroll
        for (int ds = 0; ds < 4; ds++) {
            bf16x8 v = *(const bf16x8*)(Qp + (qs * 32 + c) * Dh + ds * 16 + hi * 8);
            #pragma unroll
            for (int i = 0; i < 8; i++) v[i] = (__bf16)(qscale * (float)v[i]);
            qf[qs][ds] = v;
        }

    f32x16 accO[2][2];                     // [qs][dt]: O[q][dt*32+c] partial
    #pragma unroll
    for (int qs = 0; qs < 2; qs++)
        #pragma unroll
        for (int dt = 0; dt < 2; dt++)
            #pragma unroll
            for (int i = 0; i < 16; i++) accO[qs][dt][i] = 0.f;
    float lsum[2] = {0.f, 0.f};

    const f32x16 z16 = {0.f, 0.f, 0.f, 0.f, 0.f, 0.f, 0.f, 0.f,
                        0.f, 0.f, 0.f, 0.f, 0.f, 0.f, 0.f, 0.f};

    // staging: linear LDS dest (gll requirement) + permuted global source col
    const int r0 = qg * 8 + (lane >> 3);             // rows 0..31 per chunk
    const int s8 = ((lane & 7) ^ (r0 & 7)) * 8;      // permuted col (elems)
    const __bf16* kg0 = Kp + (size_t)(kh * 512 + r0) * Dh + s8;
    const __bf16* kg1 = kg0 + 32 * Dh;               // (32+r0)&7 == r0&7
    const __bf16* vg0 = Vp + (size_t)r0 * Ts + kh * 512 + s8;
    const __bf16* vg1 = vg0 + (size_t)32 * Ts;

    // prologue: this quarter's chunk 0 into buf 0
    gll16(kg0, &sK[kh][0][qg * 512]);
    gll16(kg1, &sK[kh][0][2048 + qg * 512]);
    gll16(vg0, &sV[kh][0][qg * 512]);
    gll16(vg1, &sV[kh][0][2048 + qg * 512]);

    for (int j = 0; j < 8; j++) {
        const int p = j & 1;
        // own chunk-j loads (issued a full chunk of compute ago) landed:
        asm volatile("s_waitcnt vmcnt(0)" ::: "memory");
        __builtin_amdgcn_s_barrier();          // everyone's chunk j in LDS;
                                               // prior readers of buf p^1 done
        __builtin_amdgcn_sched_barrier(0);
        if (j < 7) {
            const int pn = p ^ 1;
            gll16(kg0 + (j + 1) * 4096, &sK[kh][pn][qg * 512]);
            gll16(kg1 + (j + 1) * 4096, &sK[kh][pn][2048 + qg * 512]);
            gll16(vg0 + (j + 1) * 64,   &sV[kh][pn][qg * 512]);
            gll16(vg1 + (j + 1) * 64,   &sV[kh][pn][2048 + qg * 512]);
        }
        const char* kb = (const char*)&sK[kh][p][0];
        const char* vb = (const char*)&sV[kh][p][0];

        // K fragments (A-operand): kf[kt][ds] = K[kt*32+c][ds*16+hi*8 ..+8]
        bf16x8 kf[2][4];
        #pragma unroll
        for (int kt = 0; kt < 2; kt++) {
            const char* rbase = kb + (kt * 32 + c) * 128;
            #pragma unroll
            for (int ds = 0; ds < 4; ds++)
                kf[kt][ds] = *(const bf16x8*)(rbase + ((ds * 32 + hx) ^ sw));
        }

        // QK^T: st[qs][kt] = S^T[k = kt*32 + row][q = qs*32 + c] (log2e-scaled)
        f32x16 st[2][2];
        __builtin_amdgcn_s_setprio(1);
        #pragma unroll
        for (int kt = 0; kt < 2; kt++)
            #pragma unroll
            for (int qs = 0; qs < 2; qs++)
                st[qs][kt] = __builtin_amdgcn_mfma_f32_32x32x16_bf16(
                    kf[kt][0], qf[qs][0], z16, 0, 0, 0);
        #pragma unroll
        for (int ds = 1; ds < 4; ds++)
            #pragma unroll
            for (int kt = 0; kt < 2; kt++)
                #pragma unroll
                for (int qs = 0; qs < 2; qs++)
                    st[qs][kt] = __builtin_amdgcn_mfma_f32_32x32x16_bf16(
                        kf[kt][ds], qf[qs][ds], st[qs][kt], 0, 0, 0);
        __builtin_amdgcn_s_setprio(0);

        // p = exp2(s); pack to bf16 pairs; permlane32_swap builds PV A-frags.
        bf16x8 pa[2][4];
        #pragma unroll
        for (int qs = 0; qs < 2; qs++) {
            unsigned pk[2][8];
            #pragma unroll
            for (int kt = 0; kt < 2; kt++) {
                float sum0 = 0.f, sum1 = 0.f;
                #pragma unroll
                for (int r = 0; r < 16; r++) {
                    float pv = __builtin_amdgcn_exp2f(st[qs][kt][r]);
                    st[qs][kt][r] = pv;
                    if (r & 1) sum1 += pv; else sum0 += pv;
                }
                lsum[qs] += sum0 + sum1;
                #pragma unroll
                for (int r2 = 0; r2 < 8; r2++) {
                    unsigned d;
                    asm("v_cvt_pk_bf16_f32 %0, %1, %2"
                        : "=v"(d)
                        : "v"(st[qs][kt][2 * r2]), "v"(st[qs][kt][2 * r2 + 1]));
                    pk[kt][r2] = d;
                }
            }
            #pragma unroll
            for (int s = 0; s < 4; s++) {
                const int kt = s >> 1, r4 = (s & 1) * 4;
                unsigned x0 = pk[kt][r4 + 0], y0 = pk[kt][r4 + 2];
                unsigned x1 = pk[kt][r4 + 1], y1 = pk[kt][r4 + 3];
                asm("v_permlane32_swap_b32 %0, %1" : "+v"(x0), "+v"(y0));
                asm("v_permlane32_swap_b32 %0, %1" : "+v"(x1), "+v"(y1));
                union { unsigned u[4]; bf16x8 b; } pu;
                pu.u[0] = x0; pu.u[1] = x1; pu.u[2] = y0; pu.u[3] = y1;
                pa[qs][s] = pu.b;
            }
        }

        // PV: vf (B-operand) = V^T[dt*32+c][s*16 + hi*8 + j], shared by qs
        __builtin_amdgcn_s_setprio(1);
        #pragma unroll
        for (int s = 0; s < 4; s++)
            #pragma unroll
            for (int dt = 0; dt < 2; dt++) {
                bf16x8 vf = *(const bf16x8*)(vb + (dt * 32 + c) * 128 +
                                             ((s * 32 + hx) ^ sw));
                #pragma unroll
                for (int qs = 0; qs < 2; qs++)
                    accO[qs][dt] = __builtin_amdgcn_mfma_f32_32x32x16_bf16(
                        pa[qs][s], vf, accO[qs][dt], 0, 0, 0);
            }
        __builtin_amdgcn_s_setprio(0);
    }

    __syncthreads();   // all compute done; staging LDS now dead -> reuse

    // -----------------------------------------------------------------------
    // cross-quarter tree reduction in dead staging LDS (f32 views):
    // Step A: kh=2 -> sK[qg block], kh=3 -> sV[qg block].
    // Step B: kh=0 += sK (kh=2); kh=1 += sV (kh=3), then kh=1 -> sV.
    // Step C: kh=0 += sV (kh=1), normalize, store.
    // Lane-consecutive f32 -> conflict-free. Per-qg block = 4096 f32 (16 KB).
    // -----------------------------------------------------------------------
    float* baseK = (float*)&sK[0][0][0];
    float* baseV = (float*)&sV[0][0][0];

    if (kh >= 2) {
        float* pb = (kh == 2 ? baseK : baseV) + qg * 4096;
        #pragma unroll
        for (int qs = 0; qs < 2; qs++) {
            #pragma unroll
            for (int dt = 0; dt < 2; dt++)
                #pragma unroll
                for (int r = 0; r < 16; r++)
                    pb[qs * 2048 + dt * 1024 + (r << 6) + lane] = accO[qs][dt][r];
            sLs[kh][qg][qs][lane] = lsum[qs];
        }
    }
    __syncthreads();
    if (kh == 0) {
        const float* pb = baseK + qg * 4096;
        #pragma unroll
        for (int qs = 0; qs < 2; qs++) {
            #pragma unroll
            for (int dt = 0; dt < 2; dt++)
                #pragma unroll
                for (int r = 0; r < 16; r++)
                    accO[qs][dt][r] += pb[qs * 2048 + dt * 1024 + (r << 6) + lane];
            lsum[qs] += sLs[2][qg][qs][lane];
        }
    } else if (kh == 1) {
        float* pb = baseV + qg * 4096;
        #pragma unroll
        for (int qs = 0; qs < 2; qs++) {
            #pragma unroll
            for (int dt = 0; dt < 2; dt++)
                #pragma unroll
                for (int r = 0; r < 16; r++) {
                    float v = accO[qs][dt][r] + pb[qs * 2048 + dt * 1024 + (r << 6) + lane];
                    accO[qs][dt][r] = v;
                    pb[qs * 2048 + dt * 1024 + (r << 6) + lane] = v;
                }
            sLs[1][qg][qs][lane] = lsum[qs] + sLs[3][qg][qs][lane];
        }
    }
    __syncthreads();
    if (kh == 0) {
        const float* pb = baseV + qg * 4096;
        #pragma unroll
        for (int qs = 0; qs < 2; qs++) {
            #pragma unroll
            for (int dt = 0; dt < 2; dt++)
                #pragma unroll
                for (int r = 0; r < 16; r++)
                    accO[qs][dt][r] += pb[qs * 2048 + dt * 1024 + (r << 6) + lane];
            lsum[qs] += sLs[1][qg][qs][lane];
        }

        // epilogue: fold lsum halves, divide, store [B,T,C]
        const int b = bh >> 4, h = bh & 15;
        #pragma unroll
        for (int qs = 0; qs < 2; qs++) {
            float l = lsum[qs] + __shfl_xor(lsum[qs], 32);
            float linv = 1.f / l;
            #pragma unroll
            for (int r = 0; r < 16; r++) {
                const int qrow = (r & 3) + 8 * (r >> 2) + 4 * hi;
                float inv = __shfl(linv, qrow);
                __bf16* Op = O + ((size_t)(b * Ts + q0 + qs * 32 + qrow)) * Cc +
                             h * 64 + c;
                Op[0]  = (__bf16)(accO[qs][0][r] * inv);
                Op[32] = (__bf16)(accO[qs][1][r] * inv);
            }
        }
    }
}

// ---------------------------------------------------------------------------
extern "C" void kernel_launch(void* const* d_in, const int* in_sizes, int n_in,
                              void* d_out, int out_size, void* d_ws, size_t ws_size,
                              hipStream_t stream)
{
    (void)in_sizes; (void)n_in; (void)out_size; (void)ws_size;
    const float* x     = (const float*)d_in[0];
    const float* Wqkv  = (const float*)d_in[1];
    const float* bqkv  = (const float*)d_in[2];
    const float* Wproj = (const float*)d_in[3];
    const float* bproj = (const float*)d_in[4];
    float* out = (float*)d_out;

    __bf16* ws   = (__bf16*)d_ws;
    __bf16* Qw   = ws;                          // Q,K [B,H,T,Dh]; V^T [B,H,Dh,T]
    __bf16* XbAO = ws + 3 * (size_t)BHTD;       // Xb then AO (union)  8 MB
    __bf16* Wqt  = XbAO + (size_t)Mm * Cc;      // [3072][1024]        6 MB
    __bf16* Wpt  = Wqt + (size_t)Nqkv * Cc;     // [1024][1024]        2 MB

    prep_all<<<dim3(5120), 256, 0, stream>>>(x, XbAO, Wqkv, Wqt, Wproj, Wpt);
    qkv_mfma<<<dim3(Nqkv / 128, Mm / 128), 256, 0, stream>>>(XbAO, Wqt, bqkv, Qw);
    attn_mfma<<<dim3(256), 1024, 0, stream>>>(
        Qw, Qw + BHTD, Qw + 2 * (size_t)BHTD, XbAO);   // AO overwrites Xb (dead)
    proj_mfma<<<dim3(Cc / 128, Mm / 64), 256, 0, stream>>>(XbAO, Wpt, bproj, out);
}

// Round 8
// 179.886 us; speedup vs baseline: 1.9749x; 1.9749x over previous
//
#include <hip/hip_runtime.h>
#include <hip/hip_bf16.h>
#include <math.h>

using bf16 = __hip_bfloat16;

typedef __bf16 bf16x8 __attribute__((ext_vector_type(8)));
typedef __bf16 bf16x4 __attribute__((ext_vector_type(4)));
typedef float  f32x4  __attribute__((ext_vector_type(4)));
typedef float  f32x16 __attribute__((ext_vector_type(16)));

constexpr int Bb = 2;
constexpr int Ts = 2048;
constexpr int Cc = 1024;
constexpr int Hh = 16;
constexpr int Dh = 64;
constexpr int Mm = Bb * Ts;        // 4096 rows of x
constexpr int Nqkv = 3 * Cc;       // 3072
constexpr int BHTD = Bb * Hh * Ts * Dh;  // elements per Q/K/V tensor

// async global->LDS, 16B per lane; LDS dest = wave-uniform base + lane*16
__device__ __forceinline__
void gll16(const __bf16* g, __bf16* l)
{
    __builtin_amdgcn_global_load_lds(
        (const __attribute__((address_space(1))) unsigned int*)g,
        (__attribute__((address_space(3))) unsigned int*)l,
        16, 0, 0);
}

// ---------------------------------------------------------------------------
// Merged prep: [0,4096) cvt X fp32->bf16; [4096,4864) transpose W_qkv;
// [4864,5120) transpose W_proj.
// ---------------------------------------------------------------------------
__global__ __launch_bounds__(256)
void prep_all(const float* __restrict__ x, __bf16* __restrict__ Xb,
              const float* __restrict__ Wq, __bf16* __restrict__ Wqt,
              const float* __restrict__ Wp, __bf16* __restrict__ Wpt)
{
    __shared__ __bf16 tl[64][72];
    const int bid = blockIdx.x;
    const int t = threadIdx.x;

    if (bid < 4096) {
        int i = (bid * 256 + t) * 4;
        float4 v = *(const float4*)(x + i);
        bf16x4 o = { (__bf16)v.x, (__bf16)v.y, (__bf16)v.z, (__bf16)v.w };
        *(bf16x4*)(Xb + i) = o;
        return;
    }
    const float* W; __bf16* Wt; int cols, bx, by;
    if (bid < 4096 + 768) {
        W = Wq; Wt = Wqt; cols = Nqkv;
        bx = (bid - 4096) % 48; by = (bid - 4096) / 48;
    } else {
        W = Wp; Wt = Wpt; cols = Cc;
        bx = (bid - 4864) % 16; by = (bid - 4864) / 16;
    }
    const int c0 = bx * 64;   // N dim
    const int r0 = by * 64;   // K dim (1024)
    #pragma unroll
    for (int i = 0; i < 4; i++) {
        int e = t + 256 * i;
        int r = e >> 4, c4 = (e & 15) * 4;
        float4 v = *(const float4*)(W + (r0 + r) * cols + c0 + c4);
        bf16x4 o = { (__bf16)v.x, (__bf16)v.y, (__bf16)v.z, (__bf16)v.w };
        *(bf16x4*)&tl[r][c4] = o;
    }
    __syncthreads();
    #pragma unroll
    for (int i = 0; i < 4; i++) {
        int e = t + 256 * i;
        int n = e >> 4, k4 = (e & 15) * 4;
        bf16x4 o = { tl[k4][n], tl[k4 + 1][n], tl[k4 + 2][n], tl[k4 + 3][n] };
        *(bf16x4*)(Wt + (c0 + n) * 1024 + r0 + k4) = o;
    }
}

// ---------------------------------------------------------------------------
// MFMA GEMM core (R9-proven m97 structure), templated over BM (A-tile rows).
// BM=128: 4 waves x 64x64 (qkv, 3 blocks/CU). BM=64: 4 waves x 32x64
// (proj, 512-block grid -> 2 blocks/CU for cross-block overlap).
// BK=32, global_load_lds width-16 into unpadded LDS.
// C/D layout: col=l16, row=quad*4+r.
// ---------------------------------------------------------------------------
template<int BM>
__device__ __forceinline__
void gemm_core(const __bf16* __restrict__ A, const __bf16* __restrict__ Bt,
               int m0, int n0, int wm, int wn, int quad, int l16, int t,
               f32x4 (&acc)[4][4])
{
    __shared__ __bf16 Al[BM][32];
    __shared__ __bf16 Bl[128][32];

    constexpr int MT = BM / 32;        // m-subtiles per wave
    const int wave = t >> 6;
    const int lane = t & 63;
    const int srow = lane >> 2;        // 0..15
    const int scol = (lane & 3) * 8;   // 0,8,16,24

    const __bf16* Ag = A  + (size_t)(m0 + wave * 16 + srow) * 1024 + scol;
    const __bf16* Bg = Bt + (size_t)(n0 + wave * 16 + srow) * 1024 + scol;
    __bf16* Al_lo = &Al[wave * 16][0];
    __bf16* Bl_lo = &Bl[wave * 16][0];
    __bf16* Bl_hi = &Bl[64 + wave * 16][0];

    for (int k0 = 0; k0 < 1024; k0 += 32) {
        gll16(Ag + k0, Al_lo);
        if constexpr (BM == 128) {
            __bf16* Al_hi = &Al[64 + wave * 16][0];
            gll16(Ag + k0 + 64 * 1024, Al_hi);
        }
        gll16(Bg + k0,             Bl_lo);
        gll16(Bg + k0 + 64 * 1024, Bl_hi);
        __syncthreads();
        bf16x8 af[MT], bfr[4];
        #pragma unroll
        for (int mt = 0; mt < MT; mt++)
            af[mt] = *(const bf16x8*)&Al[wm * (BM / 2) + mt * 16 + l16][quad * 8];
        #pragma unroll
        for (int nt = 0; nt < 4; nt++)
            bfr[nt] = *(const bf16x8*)&Bl[wn * 64 + nt * 16 + l16][quad * 8];
        #pragma unroll
        for (int mt = 0; mt < MT; mt++)
            #pragma unroll
            for (int nt = 0; nt < 4; nt++)
                acc[mt][nt] = __builtin_amdgcn_mfma_f32_16x16x32_bf16(
                    af[mt], bfr[nt], acc[mt][nt], 0, 0, 0);
        __syncthreads();
    }
}

// QKV: bias + scatter. Q,K -> [B,H,T,Dh] via dedicated-LDS coalescing
// (bf16-typed wave-private buffer; NOT aliased with gemm staging);
// V -> [B,H,Dh,T] transposed, packed 8B direct stores.
__global__ __launch_bounds__(256)
void qkv_mfma(const __bf16* __restrict__ A, const __bf16* __restrict__ Bt,
              const float* __restrict__ bias, __bf16* __restrict__ qkv)
{
    __shared__ __bf16 ebuf[4][64][72];   // per-wave epilogue tile [m-row][d]

    const int t    = threadIdx.x;
    const int wave = t >> 6;
    const int lane = t & 63;
    const int quad = lane >> 4;
    const int l16  = lane & 15;
    const int wm   = wave >> 1, wn = wave & 1;
    const int n0 = blockIdx.x * 128;
    const int m0 = blockIdx.y * 128;

    f32x4 acc[4][4];
    #pragma unroll
    for (int i = 0; i < 4; i++)
        #pragma unroll
        for (int j = 0; j < 4; j++)
            acc[i][j] = f32x4{0.f, 0.f, 0.f, 0.f};

    gemm_core<128>(A, Bt, m0, n0, wm, wn, quad, l16, t, acc);

    // wave-uniform head info (wave n-range = 64 = one head's Dh)
    const int nw0 = n0 + wn * 64;
    const int which = nw0 >> 10;
    const int h = (nw0 & 1023) >> 6;

    if (which == 2) {
        // V^T: [b][h][d][tt], r=0..3 consecutive tt -> one 8B store
        #pragma unroll
        for (int nt = 0; nt < 4; nt++) {
            int d = nt * 16 + l16;
            float bs = bias[nw0 + nt * 16 + l16];
            #pragma unroll
            for (int mt = 0; mt < 4; mt++) {
                int m = m0 + wm * 64 + mt * 16 + quad * 4;
                int b = m >> 11;
                int tt = m & 2047;
                bf16x4 o = { (__bf16)(acc[mt][nt][0] + bs),
                             (__bf16)(acc[mt][nt][1] + bs),
                             (__bf16)(acc[mt][nt][2] + bs),
                             (__bf16)(acc[mt][nt][3] + bs) };
                *(bf16x4*)&qkv[2 * (size_t)BHTD +
                               (((size_t)(b * 16 + h) * 64 + d) * 2048 + tt)] = o;
            }
        }
    } else {
        // Q/K: stage wave's 64(m) x 64(d) tile in wave-private LDS,
        // then 8 coalesced 16B global stores per lane.
        #pragma unroll
        for (int nt = 0; nt < 4; nt++) {
            float bs = bias[nw0 + nt * 16 + l16];
            #pragma unroll
            for (int mt = 0; mt < 4; mt++)
                #pragma unroll
                for (int r = 0; r < 4; r++)
                    ebuf[wave][mt * 16 + quad * 4 + r][nt * 16 + l16] =
                        (__bf16)(acc[mt][nt][r] + bs);
        }
        // wave-private: compiler orders ds_write -> ds_read via lgkmcnt
        int m = m0 + wm * 64 + lane;
        int b = m >> 11;
        int tt = m & 2047;
        __bf16* dst = &qkv[which * (size_t)BHTD +
                           (((size_t)(b * 16 + h) * 2048 + tt) * 64)];
        #pragma unroll
        for (int c = 0; c < 8; c++)
            *(bf16x8*)(dst + c * 8) = *(const bf16x8*)&ebuf[wave][lane][c * 8];
    }
}

// Proj: bias + fp32 out [4096][1024]. BM=64 tile -> 512 blocks (2/CU).
__global__ __launch_bounds__(256)
void proj_mfma(const __bf16* __restrict__ A, const __bf16* __restrict__ Bt,
               const float* __restrict__ bias, float* __restrict__ out)
{
    const int t    = threadIdx.x;
    const int wave = t >> 6;
    const int lane = t & 63;
    const int quad = lane >> 4;
    const int l16  = lane & 15;
    const int wm   = wave >> 1, wn = wave & 1;
    const int n0 = blockIdx.x * 128;
    const int m0 = blockIdx.y * 64;

    f32x4 acc[4][4];
    #pragma unroll
    for (int i = 0; i < 4; i++)
        #pragma unroll
        for (int j = 0; j < 4; j++)
            acc[i][j] = f32x4{0.f, 0.f, 0.f, 0.f};

    gemm_core<64>(A, Bt, m0, n0, wm, wn, quad, l16, t, acc);

    #pragma unroll
    for (int nt = 0; nt < 4; nt++) {
        int n = n0 + wn * 64 + nt * 16 + l16;
        float bs = bias[n];
        #pragma unroll
        for (int mt = 0; mt < 2; mt++) {
            #pragma unroll
            for (int r = 0; r < 4; r++) {
                int m = m0 + wm * 32 + mt * 16 + quad * 4 + r;
                out[m * 1024 + n] = acc[mt][nt][r] + bs;
            }
        }
    }
}

// ---------------------------------------------------------------------------
// MFMA flash attention v7 (EXACT revert to the R3-benched 45.16us kernel):
// v6 K-split structure + T3/T4/T5 schedule. 8 waves (kh, qg), grid 256.
// Triple-buffered LDS chunks; counted s_waitcnt vmcnt(4); ONE raw s_barrier
// per chunk; s_setprio(1) around MFMA clusters; st zero-init elided.
// Register budget note (R6 lesson): 64 q/wave needs ~180 regs -> 2 waves/SIMD
// is the cap; 4-waves/SIMD designs spill catastrophically (v11: 427MB scratch).
// ---------------------------------------------------------------------------
__global__ __launch_bounds__(512, 2)
void attn_mfma(const __bf16* __restrict__ Q, const __bf16* __restrict__ K,
               const __bf16* __restrict__ VT, __bf16* __restrict__ O)
{
    __shared__ __bf16 sK[2][3][64 * 64];   // [kh][buf][k_local*64+d] swizzled
    __shared__ __bf16 sV[2][3][64 * 64];   // [kh][buf][d*64+k_local] swizzled
    __shared__ float  slsum[4][2][64];     // [qg][qs][lane] kh=1 partials

    const int t    = threadIdx.x;
    const int wave = t >> 6;
    const int lane = t & 63;
    const int qg   = wave & 3;             // q-group 0..3
    const int kh   = wave >> 2;            // k-half 0..1
    const int c    = lane & 31;
    const int hi   = lane >> 5;
    const int hx   = hi * 16;              // byte offset of the 8-elem half
    const int sw   = (c & 7) << 4;         // read-side XOR swizzle

    const int blk = blockIdx.x;
    const int bh  = blk & 31;
    const int qc  = blk >> 5;              // 0..7
    const int q0  = qc * 256 + qg * 64;

    const __bf16* Qp = Q  + ((size_t)bh * Ts + q0) * Dh;
    const __bf16* Kp = K  + (size_t)bh * Ts * Dh;
    const __bf16* Vp = VT + (size_t)bh * Dh * Ts;   // [64][2048]

    // Q fragments (B-operand of mfma(K,Q)), pre-scaled by log2e/sqrt(Dh)
    const float qscale = 0.125f * 1.44269504088896f;
    bf16x8 qf[2][4];
    #pragma unroll
    for (int qs = 0; qs < 2; qs++)
        #pragma unroll
        for (int ds = 0; ds < 4; ds++) {
            bf16x8 v = *(const bf16x8*)(Qp + (qs * 32 + c) * Dh + ds * 16 + hi * 8);
            #pragma unroll
            for (int i = 0; i < 8; i++) v[i] = (__bf16)(qscale * (float)v[i]);
            qf[qs][ds] = v;
        }

    f32x16 accO[2][2];                     // [qs][dt]: O[q][dt*32+c] partial
    #pragma unroll
    for (int qs = 0; qs < 2; qs++)
        #pragma unroll
        for (int dt = 0; dt < 2; dt++)
            #pragma unroll
            for (int i = 0; i < 16; i++) accO[qs][dt][i] = 0.f;
    float lsum[2] = {0.f, 0.f};

    const f32x16 z16 = {0.f, 0.f, 0.f, 0.f, 0.f, 0.f, 0.f, 0.f,
                        0.f, 0.f, 0.f, 0.f, 0.f, 0.f, 0.f, 0.f};

    // staging: linear LDS dest (gll requirement) + permuted global source col
    const int r0 = qg * 8 + (lane >> 3);             // rows 0..31 per kh-half
    const int s8 = ((lane & 7) ^ (r0 & 7)) * 8;      // permuted col (elems)
    const __bf16* kg0 = Kp + (size_t)(kh * 1024 + r0) * Dh + s8;
    const __bf16* kg1 = kg0 + 32 * Dh;               // (32+r0)&7 == r0&7
    const __bf16* vg0 = Vp + (size_t)r0 * Ts + kh * 1024 + s8;
    const __bf16* vg1 = vg0 + (size_t)32 * Ts;

    // prologue: this half's chunk 0 into buf 0
    gll16(kg0, &sK[kh][0][qg * 512]);
    gll16(kg1, &sK[kh][0][2048 + qg * 512]);
    gll16(vg0, &sV[kh][0][qg * 512]);
    gll16(vg1, &sV[kh][0][2048 + qg * 512]);

    for (int j = 0; j < 16; j++) {
        const int p = j % 3;
        if (j < 15) {
            const int pn = (j + 1) % 3;
            gll16(kg0 + (j + 1) * 4096, &sK[kh][pn][qg * 512]);
            gll16(kg1 + (j + 1) * 4096, &sK[kh][pn][2048 + qg * 512]);
            gll16(vg0 + (j + 1) * 64,   &sV[kh][pn][qg * 512]);
            gll16(vg1 + (j + 1) * 64,   &sV[kh][pn][2048 + qg * 512]);
            // chunk j's loads (issued last iter) done; j+1's stay in flight
            asm volatile("s_waitcnt vmcnt(4)" ::: "memory");
        } else {
            asm volatile("s_waitcnt vmcnt(0)" ::: "memory");
        }
        __builtin_amdgcn_s_barrier();          // all waves: chunk j in LDS
        __builtin_amdgcn_sched_barrier(0);     // pin ds_reads below barrier

        const char* kb = (const char*)&sK[kh][p][0];
        const char* vb = (const char*)&sV[kh][p][0];

        // K fragments (A-operand): kf[kt][ds] = K[kt*32+c][ds*16+hi*8 ..+8]
        bf16x8 kf[2][4];
        #pragma unroll
        for (int kt = 0; kt < 2; kt++) {
            const char* rbase = kb + (kt * 32 + c) * 128;
            #pragma unroll
            for (int ds = 0; ds < 4; ds++)
                kf[kt][ds] = *(const bf16x8*)(rbase + ((ds * 32 + hx) ^ sw));
        }

        // QK^T: st[qs][kt] = S^T[k = kt*32 + row][q = qs*32 + c] (log2e-scaled)
        f32x16 st[2][2];
        __builtin_amdgcn_s_setprio(1);
        #pragma unroll
        for (int kt = 0; kt < 2; kt++)
            #pragma unroll
            for (int qs = 0; qs < 2; qs++)
                st[qs][kt] = __builtin_amdgcn_mfma_f32_32x32x16_bf16(
                    kf[kt][0], qf[qs][0], z16, 0, 0, 0);
        #pragma unroll
        for (int ds = 1; ds < 4; ds++)
            #pragma unroll
            for (int kt = 0; kt < 2; kt++)
                #pragma unroll
                for (int qs = 0; qs < 2; qs++)
                    st[qs][kt] = __builtin_amdgcn_mfma_f32_32x32x16_bf16(
                        kf[kt][ds], qf[qs][ds], st[qs][kt], 0, 0, 0);
        __builtin_amdgcn_s_setprio(0);

        // p = exp2(s); pack to bf16 pairs; permlane32_swap builds PV A-frags.
        bf16x8 pa[2][4];
        #pragma unroll
        for (int qs = 0; qs < 2; qs++) {
            unsigned pk[2][8];
            #pragma unroll
            for (int kt = 0; kt < 2; kt++) {
                float sum0 = 0.f, sum1 = 0.f;
                #pragma unroll
                for (int r = 0; r < 16; r++) {
                    float pv = __builtin_amdgcn_exp2f(st[qs][kt][r]);
                    st[qs][kt][r] = pv;
                    if (r & 1) sum1 += pv; else sum0 += pv;
                }
                lsum[qs] += sum0 + sum1;
                #pragma unroll
                for (int r2 = 0; r2 < 8; r2++) {
                    unsigned d;
                    asm("v_cvt_pk_bf16_f32 %0, %1, %2"
                        : "=v"(d)
                        : "v"(st[qs][kt][2 * r2]), "v"(st[qs][kt][2 * r2 + 1]));
                    pk[kt][r2] = d;
                }
            }
            #pragma unroll
            for (int s = 0; s < 4; s++) {
                const int kt = s >> 1, r4 = (s & 1) * 4;
                unsigned x0 = pk[kt][r4 + 0], y0 = pk[kt][r4 + 2];
                unsigned x1 = pk[kt][r4 + 1], y1 = pk[kt][r4 + 3];
                asm("v_permlane32_swap_b32 %0, %1" : "+v"(x0), "+v"(y0));
                asm("v_permlane32_swap_b32 %0, %1" : "+v"(x1), "+v"(y1));
                union { unsigned u[4]; bf16x8 b; } pu;
                pu.u[0] = x0; pu.u[1] = x1; pu.u[2] = y0; pu.u[3] = y1;
                pa[qs][s] = pu.b;
            }
        }

        // PV: vf (B-operand) = V^T[dt*32+c][s*16 + hi*8 + j], shared by qs
        __builtin_amdgcn_s_setprio(1);
        #pragma unroll
        for (int s = 0; s < 4; s++)
            #pragma unroll
            for (int dt = 0; dt < 2; dt++) {
                bf16x8 vf = *(const bf16x8*)(vb + (dt * 32 + c) * 128 +
                                             ((s * 32 + hx) ^ sw));
                #pragma unroll
                for (int qs = 0; qs < 2; qs++)
                    accO[qs][dt] = __builtin_amdgcn_mfma_f32_32x32x16_bf16(
                        pa[qs][s], vf, accO[qs][dt], 0, 0, 0);
            }
        __builtin_amdgcn_s_setprio(0);
        // no trailing barrier: triple-buffer guarantees buf reuse distance 3
    }

    __syncthreads();   // all compute done; staging LDS now dead -> reuse

    // -----------------------------------------------------------------------
    // cross-half reduction: kh=1 publishes partials into (dead) staging LDS,
    // kh=0 adds and runs the epilogue. Lane-consecutive f32 -> conflict-free.
    // -----------------------------------------------------------------------
    float* pb = (qg < 2) ? (float*)&sK[0][0][0] + qg * 4096
                         : (float*)&sV[0][0][0] + (qg - 2) * 4096;
    if (kh == 1) {
        #pragma unroll
        for (int qs = 0; qs < 2; qs++) {
            #pragma unroll
            for (int dt = 0; dt < 2; dt++)
                #pragma unroll
                for (int r = 0; r < 16; r++)
                    pb[((qs * 2 + dt) << 10) + (r << 6) + lane] = accO[qs][dt][r];
            slsum[qg][qs][lane] = lsum[qs];
        }
    }
    __syncthreads();
    if (kh == 0) {
        #pragma unroll
        for (int qs = 0; qs < 2; qs++) {
            #pragma unroll
            for (int dt = 0; dt < 2; dt++)
                #pragma unroll
                for (int r = 0; r < 16; r++)
                    accO[qs][dt][r] += pb[((qs * 2 + dt) << 10) + (r << 6) + lane];
            lsum[qs] += slsum[qg][qs][lane];
        }

        // epilogue: fold lsum halves, divide, store [B,T,C]
        const int b = bh >> 4, h = bh & 15;
        #pragma unroll
        for (int qs = 0; qs < 2; qs++) {
            float l = lsum[qs] + __shfl_xor(lsum[qs], 32);
            float linv = 1.f / l;
            #pragma unroll
            for (int r = 0; r < 16; r++) {
                const int qrow = (r & 3) + 8 * (r >> 2) + 4 * hi;
                float inv = __shfl(linv, qrow);
                __bf16* Op = O + ((size_t)(b * Ts + q0 + qs * 32 + qrow)) * Cc +
                             h * 64 + c;
                Op[0]  = (__bf16)(accO[qs][0][r] * inv);
                Op[32] = (__bf16)(accO[qs][1][r] * inv);
            }
        }
    }
}

// ---------------------------------------------------------------------------
extern "C" void kernel_launch(void* const* d_in, const int* in_sizes, int n_in,
                              void* d_out, int out_size, void* d_ws, size_t ws_size,
                              hipStream_t stream)
{
    (void)in_sizes; (void)n_in; (void)out_size; (void)ws_size;
    const float* x     = (const float*)d_in[0];
    const float* Wqkv  = (const float*)d_in[1];
    const float* bqkv  = (const float*)d_in[2];
    const float* Wproj = (const float*)d_in[3];
    const float* bproj = (const float*)d_in[4];
    float* out = (float*)d_out;

    __bf16* ws   = (__bf16*)d_ws;
    __bf16* Qw   = ws;                          // Q,K [B,H,T,Dh]; V^T [B,H,Dh,T]
    __bf16* XbAO = ws + 3 * (size_t)BHTD;       // Xb then AO (union)  8 MB
    __bf16* Wqt  = XbAO + (size_t)Mm * Cc;      // [3072][1024]        6 MB
    __bf16* Wpt  = Wqt + (size_t)Nqkv * Cc;     // [1024][1024]        2 MB

    prep_all<<<dim3(5120), 256, 0, stream>>>(x, XbAO, Wqkv, Wqt, Wproj, Wpt);
    qkv_mfma<<<dim3(Nqkv / 128, Mm / 128), 256, 0, stream>>>(XbAO, Wqt, bqkv, Qw);
    attn_mfma<<<dim3(256), 512, 0, stream>>>(
        Qw, Qw + BHTD, Qw + 2 * (size_t)BHTD, XbAO);   // AO overwrites Xb (dead)
    proj_mfma<<<dim3(Cc / 128, Mm / 64), 256, 0, stream>>>(XbAO, Wpt, bproj, out);
}